// Round 4
// baseline (202.134 us; speedup 1.0000x reference)
//
#include <hip/hip_runtime.h>
#include <hip/hip_bf16.h>
#include <math.h>

// ---------------------------------------------------------------------------
// Fully-MFMA fused transformer block (R11 = R10 + grid-stride amortization):
//   - 4096 workgroups (16/CU, the LDS-capped residency), each processing 4
//     consecutive token-blocks; weight/bias fragments hoisted out of the loop
//     (prologue was ~10-15% of per-wave issue work, repeated 16384x in R10).
//   - Scores in log2 domain (0.25*log2e folded into Wq) -> native v_exp_f32.
//   - 1/l via v_rcp_f32 (l in [1,64], well-conditioned).
//   All GEMMs single-bf16; softmax/LN/residual/gelu fp32, two-pass variance.
// One wave (64 threads) per token-block of 64 tokens x 16 channels.
// v_mfma_f32_16x16x32_bf16 layouts (m89/m91-verified):
//   C/D: D[m=quad*4+reg][n=lane&15]
//   A:   A[m=lane&15][k=quad*8+j]   (word p = elements 2p(lo16), 2p+1(hi16))
//   B:   B[k=quad*8+j][n=lane&15]
// ---------------------------------------------------------------------------

typedef __attribute__((ext_vector_type(8))) short bf8;   // 8 bf16 (4 VGPRs)
typedef __attribute__((ext_vector_type(4))) float f4;    // 4 fp32 (C/D frag)

union FragU { uint4 u4; uint u[4]; bf8 b; };

#define ITERS 4

__device__ __forceinline__ uint packbf(float lo, float hi) {   // lo -> bits[15:0]
    union { __hip_bfloat162 h; uint u; } c;
    c.h = __float22bfloat162_rn(make_float2(lo, hi));
    return c.u;
}

// exact-gelu via A&S 7.1.26 erf (max err 1.5e-7), branch-free
__device__ __forceinline__ float gelu_f(float u) {
    float z  = fabsf(u) * 0.70710678118654752f;
    float tt = __builtin_amdgcn_rcpf(1.f + 0.3275911f * z);
    float poly = ((((1.061405429f * tt - 1.453152027f) * tt + 1.421413741f) * tt
                   - 0.284496736f) * tt + 0.254829592f) * tt;
    float erfz = 1.f - poly * __expf(-z * z);
    return 0.5f * u * (1.f + copysignf(erfz, u));
}

#define MFMA(a, b, c) __builtin_amdgcn_mfma_f32_16x16x32_bf16(a, b, c, 0, 0, 0)

// LDS arena (word units), 2304 words = 9216 B. Regions (words):
//  Phase A out: sQ bf16-pairs [64][12] @0, sK [64][12] @768, sV [16][36] @1536
//  Phase P:     sP bf16 [64 queries][36] @0 (V already in regs; over dead Q/K)
//  Phase LN2:   sH2 [64][12] @0          (over dead sP head)
//  Phase FFN1:  sU [64][20] @768         (over dead sK/sV/sP)
//  Phase out:   sF f32 [64][20] @0       (over dead sH2 + sU head)
#define OQ  0
#define OK  768
#define OV  1536
#define OP  0
#define OH2 0
#define OU  768
#define OF  0
#define ARENA 2304

// bf16 B-fragment: B[k=kb+j][n], row-major W, leading dim ld
__device__ __forceinline__ void loadWfrag(const float* __restrict__ W, int ld,
                                          int n, int kb, bool valid, float scale,
                                          bf8& hf) {
    FragU H;
    if (valid) {
        #pragma unroll
        for (int p = 0; p < 4; ++p)
            H.u[p] = packbf(W[(kb+2*p)*ld+n]*scale, W[(kb+2*p+1)*ld+n]*scale);
    } else {
        H.u4 = make_uint4(0u,0u,0u,0u);
    }
    hf = H.b;
}

__global__ __launch_bounds__(64, 4)
void tb_kernel(const float* __restrict__ x,
               const float* __restrict__ Wk, const float* __restrict__ Wq,
               const float* __restrict__ Wv,
               const float* __restrict__ ln1g, const float* __restrict__ ln1b,
               const float* __restrict__ ln2g, const float* __restrict__ ln2b,
               const float* __restrict__ W1, const float* __restrict__ b1,
               const float* __restrict__ W2, const float* __restrict__ b2,
               float* __restrict__ out, int nblk)
{
    __shared__ __align__(16) uint lds[ARENA];
    const int lane = threadIdx.x;
    const int c15  = lane & 15;
    const int quad = lane >> 4;
    const int quad4 = quad << 2;
    const f4 z4 = {0.f, 0.f, 0.f, 0.f};
    const bool kv = (quad < 2);          // K=16 mats: only quads 0,1 carry data
    const int  kb = quad * 8;
    const bool wrE = ((c15 & 1) == 0);

    // ---- loop-invariant fragments (amortized over ITERS blocks)
    // Wq scale folds 1/sqrt(16) AND log2(e): scores land in log2 domain.
    bf8 fWq, fWk, fWv;
    loadWfrag(Wq, 16, c15, kb, kv, 0.25f*1.44269504f, fWq);
    loadWfrag(Wk, 16, c15, kb, kv, 1.0f,  fWk);
    loadWfrag(Wv, 16, c15, kb, kv, 1.0f,  fWv);
    bf8 fW1a, fW1b, fW2f;
    loadWfrag(W1, 32, c15,      kb, kv,   1.0f, fW1a);
    loadWfrag(W1, 32, c15 + 16, kb, kv,   1.0f, fW1b);
    loadWfrag(W2, 16, c15,      kb, true, 1.0f, fW2f);   // K=32 native, all quads
    const float bu0 = b1[c15], bu1 = b1[16 + c15], bo = b2[c15];

    #pragma unroll 1
    for (int it = 0; it < ITERS; ++it) {
        const int blk = blockIdx.x * ITERS + it;
        if (blk >= nblk) break;
        const size_t base = (size_t)blk * (64 * 16);

        // ---- LN1 (fp32, TWO-PASS variance) -> bf16 A-fragments
        bf8 ah[4];
        {
            float gg[8], bb[8];
            if (kv) {
                const float4* gp = (const float4*)(ln1g + kb);
                const float4* bp = (const float4*)(ln1b + kb);
                float4 g0 = gp[0], g1 = gp[1], b0 = bp[0], b1_ = bp[1];
                gg[0]=g0.x; gg[1]=g0.y; gg[2]=g0.z; gg[3]=g0.w;
                gg[4]=g1.x; gg[5]=g1.y; gg[6]=g1.z; gg[7]=g1.w;
                bb[0]=b0.x; bb[1]=b0.y; bb[2]=b0.z; bb[3]=b0.w;
                bb[4]=b1_.x; bb[5]=b1_.y; bb[6]=b1_.z; bb[7]=b1_.w;
            }
            #pragma unroll
            for (int mt = 0; mt < 4; ++mt) {
                FragU Ah;
                if (kv) {
                    const float4* xp = (const float4*)(x + base + (size_t)(mt*16 + c15)*16 + kb);
                    float4 v0 = xp[0], v1 = xp[1];
                    float xv[8] = {v0.x,v0.y,v0.z,v0.w, v1.x,v1.y,v1.z,v1.w};
                    float s = 0.f;
                    #pragma unroll
                    for (int j = 0; j < 8; ++j) s += xv[j];
                    s  += __shfl_xor(s, 16);    // combine half-rows (quads 0,1)
                    float mu = s * 0.0625f;
                    float s2 = 0.f;
                    #pragma unroll
                    for (int j = 0; j < 8; ++j) { float d = xv[j] - mu; s2 += d*d; }
                    s2 += __shfl_xor(s2, 16);   // two-pass variance
                    float var  = s2 * 0.0625f;
                    float rstd = rsqrtf(var + 1e-5f);
                    float h[8];
                    #pragma unroll
                    for (int j = 0; j < 8; ++j) h[j] = (xv[j]-mu)*rstd*gg[j] + bb[j];
                    #pragma unroll
                    for (int p = 0; p < 4; ++p) Ah.u[p] = packbf(h[2*p], h[2*p+1]);
                } else {
                    Ah.u4 = make_uint4(0u,0u,0u,0u);
                }
                ah[mt] = Ah.b;
            }
        }

        // ---- projections -> packed bf16 LDS tiles
        //  sQ/sK: [tok][chpair] stride 12; sV: [ch][tokpair] stride 36
        #pragma unroll
        for (int mt = 0; mt < 4; ++mt) {
            f4 qc = MFMA(ah[mt], fWq, z4);
            f4 kc = MFMA(ah[mt], fWk, z4);
            f4 vc = MFMA(ah[mt], fWv, z4);
            #pragma unroll
            for (int r = 0; r < 4; ++r) {
                const int tok = mt*16 + quad4 + r;
                float qo = __shfl_xor(qc[r], 1);
                float ko = __shfl_xor(kc[r], 1);
                if (wrE) {
                    lds[OQ + tok*12 + (c15>>1)] = packbf(qc[r], qo);
                    lds[OK + tok*12 + (c15>>1)] = packbf(kc[r], ko);
                }
            }
            *(uint2*)(lds + OV + c15*36 + mt*8 + quad*2) =
                make_uint2(packbf(vc[0], vc[1]), packbf(vc[2], vc[3]));
        }
        __syncthreads();   // B1: packed Q/K/V visible

        // ---- S^T = K.Q^T, causal triangle only (10 MFMAs)
        bf8 qb[4];                     // B-frags: B[k=ch][n=query] per query-tile
        #pragma unroll
        for (int qt = 0; qt < 4; ++qt) {
            FragU H;
            if (kv) H.u4 = *(const uint4*)(lds + OQ + (qt*16 + c15)*12 + quad4);
            else    H.u4 = make_uint4(0u,0u,0u,0u);
            qb[qt] = H.b;
        }
        f4 st[4][4];                   // st[kt][qt]: S^T[key=kt*16+quad4+r][query=qt*16+c15]
        #pragma unroll
        for (int kt = 0; kt < 4; ++kt) {
            FragU H;                   // A-frag: A[m=key][k=ch]
            if (kv) H.u4 = *(const uint4*)(lds + OK + (kt*16 + c15)*12 + quad4);
            else    H.u4 = make_uint4(0u,0u,0u,0u);
            bf8 ka = H.b;
            #pragma unroll
            for (int qt = 3; qt >= 0; --qt)
                if (qt >= kt)          // compile-time (unrolled): triangle only
                    st[kt][qt] = MFMA(ka, qb[qt], z4);
        }
        // causal mask on diagonal tiles
        #pragma unroll
        for (int qt = 0; qt < 4; ++qt)
            #pragma unroll
            for (int r = 0; r < 4; ++r)
                st[qt][qt][r] = (quad4 + r <= c15) ? st[qt][qt][r] : -1e30f;

        // ---- direct softmax per query column (scores already in log2 units)
        float linv[4];
        #pragma unroll
        for (int qt = 0; qt < 4; ++qt) {
            float mx = st[0][qt][0];
            #pragma unroll
            for (int kt = 0; kt < 4; ++kt) {
                if (kt <= qt) {
                    #pragma unroll
                    for (int r = 0; r < 4; ++r) mx = fmaxf(mx, st[kt][qt][r]);
                }
            }
            mx = fmaxf(mx, __shfl_xor(mx, 16));
            mx = fmaxf(mx, __shfl_xor(mx, 32));
            float l = 0.f;
            #pragma unroll
            for (int kt = 0; kt < 4; ++kt) {
                if (kt <= qt) {
                    #pragma unroll
                    for (int r = 0; r < 4; ++r) {
                        float p = __builtin_amdgcn_exp2f(st[kt][qt][r] - mx);
                        st[kt][qt][r] = p;
                        l += p;
                    }
                }
            }
            l += __shfl_xor(l, 16);
            l += __shfl_xor(l, 32);
            linv[qt] = __builtin_amdgcn_rcpf(l);   // l in [1,64]
        }

        // ---- V A-fragments into registers BEFORE sP overwrites the arena
        bf8 va[2];                     // A[m=ch][k=key]
        #pragma unroll
        for (int kc = 0; kc < 2; ++kc) {
            FragU H;
            H.u4 = *(const uint4*)(lds + OV + c15*36 + kc*16 + quad4);
            va[kc] = H.b;
        }
        __syncthreads();   // B2a: all Q/K/V reads done; sP region writable

        // ---- pack P (bf16, unnormalized, in-lane key-pairs) -> sP [query][36]
        #pragma unroll
        for (int qt = 0; qt < 4; ++qt) {
            const int rowo = OP + (qt*16 + c15)*36 + quad*2;
            #pragma unroll
            for (int kt = 0; kt < 4; ++kt) {
                uint2 w;
                if (kt <= qt) {
                    w.x = packbf(st[kt][qt][0], st[kt][qt][1]);
                    w.y = packbf(st[kt][qt][2], st[kt][qt][3]);
                } else w = make_uint2(0u, 0u);
                *(uint2*)(lds + rowo + kt*8) = w;
            }
        }
        __syncthreads();   // B2b: sP visible

        // ---- y^T = V^T.P (6 MFMAs)
        f4 yt[4];                      // yt[qt]: y[query=qt*16+c15][ch=quad4+r]
        #pragma unroll
        for (int qt = 0; qt < 4; ++qt) {
            f4 acc = z4;
            #pragma unroll
            for (int kc = 0; kc < 2; ++kc) {
                if (kc == 0 || qt >= 2) {   // keys>=32 only for queries>=32
                    FragU P_;
                    P_.u4 = *(const uint4*)(lds + OP + (qt*16 + c15)*36 + kc*16 + quad4);
                    acc = MFMA(va[kc], P_.b, acc);
                }
            }
            yt[qt] = acc;
        }

        // ---- residual 1 (y layout: query=qt*16+c15, ch=quad4+r)
        float x2v[4][4];
        #pragma unroll
        for (int qt = 0; qt < 4; ++qt) {
            float4 xv = *(const float4*)(x + base + (size_t)(qt*16 + c15)*16 + quad4);
            const float li = linv[qt];
            x2v[qt][0] = xv.x + yt[qt][0]*li;
            x2v[qt][1] = xv.y + yt[qt][1]*li;
            x2v[qt][2] = xv.z + yt[qt][2]*li;
            x2v[qt][3] = xv.w + yt[qt][3]*li;
        }
        __syncthreads();   // B3: sP reads done; sH2 region writable

        // ---- LN2 (two-pass, cross-quad butterfly) -> packed bf16 h2
        {
            float4 g2  = *(const float4*)(ln2g + quad4);
            float4 b2v = *(const float4*)(ln2b + quad4);
            #pragma unroll
            for (int qt = 0; qt < 4; ++qt) {
                float s = x2v[qt][0]+x2v[qt][1]+x2v[qt][2]+x2v[qt][3];
                s += __shfl_xor(s, 16); s += __shfl_xor(s, 32);
                float mu = s * 0.0625f;
                float d0 = x2v[qt][0]-mu, d1 = x2v[qt][1]-mu,
                      d2 = x2v[qt][2]-mu, d3 = x2v[qt][3]-mu;
                float s2 = d0*d0 + d1*d1 + d2*d2 + d3*d3;
                s2 += __shfl_xor(s2, 16); s2 += __shfl_xor(s2, 32);
                float rstd = rsqrtf(s2 * 0.0625f + 1e-5f);
                float h0 = d0*rstd*g2.x + b2v.x;
                float h1 = d1*rstd*g2.y + b2v.y;
                float h2_ = d2*rstd*g2.z + b2v.z;
                float h3 = d3*rstd*g2.w + b2v.w;
                *(uint2*)(lds + OH2 + (qt*16 + c15)*12 + quad*2) =
                    make_uint2(packbf(h0, h1), packbf(h2_, h3));
            }
        }
        __syncthreads();   // B4: sH2 visible

        // ---- h2 A-fragments
        bf8 a2[4];
        #pragma unroll
        for (int i = 0; i < 4; ++i) {
            FragU H;
            if (kv) H.u4 = *(const uint4*)(lds + OH2 + (i*16 + c15)*12 + quad4);
            else    H.u4 = make_uint4(0u,0u,0u,0u);
            a2[i] = H.b;
        }

        // ---- FFN1 (8 MFMAs) + gelu -> sU [64][20] @768 (disjoint from sH2)
        {
            f4 cb0 = {bu0, bu0, bu0, bu0};
            f4 cb1 = {bu1, bu1, bu1, bu1};
            #pragma unroll
            for (int mt = 0; mt < 4; ++mt) {
                f4 u0 = MFMA(a2[mt], fW1a, cb0);
                f4 u1 = MFMA(a2[mt], fW1b, cb1);
                #pragma unroll
                for (int r = 0; r < 4; ++r) {
                    float g0 = gelu_f(u0[r]);
                    float g1 = gelu_f(u1[r]);
                    float go0 = __shfl_xor(g0, 1);
                    float go1 = __shfl_xor(g1, 1);
                    if (wrE) {
                        const int row = mt*16 + quad4 + r;
                        lds[OU + row*20 +     (c15 >> 1)] = packbf(g0, go0);
                        lds[OU + row*20 + 8 + (c15 >> 1)] = packbf(g1, go1);
                    }
                }
            }
        }
        __syncthreads();   // B5: sU visible

        // ---- FFN2 (native K=32, 4 MFMAs)
        f4 fo[4];
        {
            f4 cb = {bo, bo, bo, bo};
            #pragma unroll
            for (int mt = 0; mt < 4; ++mt) {
                FragU H;                // A[m=tok][k=quad*8+j] spans all 32 ff dims
                H.u4 = *(const uint4*)(lds + OU + (mt*16 + c15)*20 + quad4);
                fo[mt] = MFMA(H.b, fW2f, cb);
            }
        }
        __syncthreads();   // B6: sU reads done; sF @0 writable
        #pragma unroll
        for (int mt = 0; mt < 4; ++mt)
            #pragma unroll
            for (int r = 0; r < 4; ++r)
                lds[OF + (mt*16 + quad4 + r)*20 + c15] = __float_as_uint(fo[mt][r]);
        __syncthreads();   // B7: sF visible

        // ---- final residual + coalesced store
        #pragma unroll
        for (int qt = 0; qt < 4; ++qt) {
            FragU F;
            F.u4 = *(const uint4*)(lds + OF + (qt*16 + c15)*20 + quad4);
            float4 o;
            o.x = x2v[qt][0] + __uint_as_float(F.u[0]);
            o.y = x2v[qt][1] + __uint_as_float(F.u[1]);
            o.z = x2v[qt][2] + __uint_as_float(F.u[2]);
            o.w = x2v[qt][3] + __uint_as_float(F.u[3]);
            *(float4*)(out + base + (size_t)(qt*16 + c15)*16 + quad4) = o;
        }
        __syncthreads();   // loop boundary: sF reads done before next proj writes
    }
}

extern "C" void kernel_launch(void* const* d_in, const int* in_sizes, int n_in,
                              void* d_out, int out_size, void* d_ws, size_t ws_size,
                              hipStream_t stream) {
    const float* x     = (const float*)d_in[0];
    const float* Wk    = (const float*)d_in[1];
    const float* Wq    = (const float*)d_in[2];
    const float* Wv    = (const float*)d_in[3];
    const float* ln1_g = (const float*)d_in[4];
    const float* ln1_b = (const float*)d_in[5];
    const float* ln2_g = (const float*)d_in[6];
    const float* ln2_b = (const float*)d_in[7];
    const float* W1    = (const float*)d_in[8];
    const float* b1    = (const float*)d_in[9];
    const float* W2    = (const float*)d_in[10];
    const float* b2    = (const float*)d_in[11];
    float* out = (float*)d_out;

    const int n_blocks = in_sizes[0] / (64 * 16);   // 16384
    const int nwg = (n_blocks + ITERS - 1) / ITERS; // 4096 -> 16 wg/CU
    tb_kernel<<<nwg, 64, 0, stream>>>(
        x, Wk, Wq, Wv, ln1_g, ln1_b, ln2_g, ln2_b, W1, b1, W2, b2, out, n_blocks);
}

// Round 5
// 173.413 us; speedup vs baseline: 1.1656x; 1.1656x over previous
//
#include <hip/hip_runtime.h>
#include <hip/hip_bf16.h>

// ---------------------------------------------------------------------------
// R12 = R10 (16384 one-block workgroups; streaming dispatch order restored)
//   + prep kernel: weight fragments / ln params / biases pre-packed into d_ws
//     (main prologue = 13 L2-hot b128 loads instead of ~56 scalar loads+packs)
//   + log2-domain scores (0.25*log2e folded into Wq at prep) -> native exp2
//   + 1/l and gelu via v_rcp; gelu in tanh form (sigmoid*u, 7 insts vs 13)
// R11 grid-stride REVERTED: it doubled HBM FETCH (L3 thrash from 4x-strided
// simultaneous footprint) and stalls ate the prologue savings.
// One wave (64 threads) per token-block of 64 tokens x 16 channels.
// v_mfma_f32_16x16x32_bf16 layouts (m89/m91-verified):
//   C/D: D[m=quad*4+reg][n=lane&15]
//   A:   A[m=lane&15][k=quad*8+j]   (word p = elements 2p(lo16), 2p+1(hi16))
//   B:   B[k=quad*8+j][n=lane&15]
// ---------------------------------------------------------------------------

typedef __attribute__((ext_vector_type(8))) short bf8;   // 8 bf16 (4 VGPRs)
typedef __attribute__((ext_vector_type(4))) float f4;    // 4 fp32 (C/D frag)

union FragU { uint4 u4; uint u[4]; bf8 b; };
union F4U  { uint4 u4; float4 f; };

__device__ __forceinline__ uint packbf(float lo, float hi) {   // lo -> bits[15:0]
    union { __hip_bfloat162 h; uint u; } c;
    c.h = __float22bfloat162_rn(make_float2(lo, hi));
    return c.u;
}

// tanh-form gelu: u * sigma(2*sqrt(2/pi)*(u + 0.044715 u^3)), exp2 domain.
// |err vs exact erf-gelu| <= ~1e-3; through W2 adds <= ~0.01 at output.
__device__ __forceinline__ float gelu_fast(float u) {
    float u2 = u * u;
    float t  = u * (-2.3022079f + -0.1029431f * u2);   // -2*log2e*c1*(1+c2 u^2)
    float e  = __builtin_amdgcn_exp2f(t);
    return u * __builtin_amdgcn_rcpf(1.f + e);
}

#define MFMA(a, b, c) __builtin_amdgcn_mfma_f32_16x16x32_bf16(a, b, c, 0, 0, 0)

// LDS arena (word units), 2304 words = 9216 B. Regions (words):
//  Phase A out: sQ bf16-pairs [64][12] @0, sK [64][12] @768, sV [16][36] @1536
//  Phase P:     sP bf16 [64 queries][36] @0 (V already in regs; over dead Q/K)
//  Phase LN2:   sH2 [64][12] @0          (over dead sP head)
//  Phase FFN1:  sU [64][20] @768         (over dead sK/sV/sP)
//  Phase out:   sF f32 [64][20] @0       (over dead sH2 + sU head)
#define OQ  0
#define OK  768
#define OV  1536
#define OP  0
#define OH2 0
#define OU  768
#define OF  0
#define ARENA 2304

// ws blob layout: per-lane 16 uint4 slots (256 B/lane, 16 KB total):
//  0..5: fWq fWk fWv fW1a fW1b fW2   (packed bf16 B-fragments)
//  6,7:  ln1g[kb..+3], ln1g[kb+4..+7]   (fp32; zeros for quads 2,3)
//  8,9:  ln1b[kb..+3], ln1b[kb+4..+7]
//  10,11: ln2g[quad4..+3], ln2b[quad4..+3]
//  12:   {b1[c15], b1[c15+16], b2[c15], 0}
#define WS_SLOTS 16

// bf16 B-fragment: B[k=kb+j][n], row-major W, leading dim ld
__device__ __forceinline__ void loadWfrag(const float* __restrict__ W, int ld,
                                          int n, int kb, bool valid, float scale,
                                          bf8& hf) {
    FragU H;
    if (valid) {
        #pragma unroll
        for (int p = 0; p < 4; ++p)
            H.u[p] = packbf(W[(kb+2*p)*ld+n]*scale, W[(kb+2*p+1)*ld+n]*scale);
    } else {
        H.u4 = make_uint4(0u,0u,0u,0u);
    }
    hf = H.b;
}

__global__ __launch_bounds__(64, 1)
void prep_kernel(const float* __restrict__ Wk, const float* __restrict__ Wq,
                 const float* __restrict__ Wv,
                 const float* __restrict__ ln1g, const float* __restrict__ ln1b,
                 const float* __restrict__ ln2g, const float* __restrict__ ln2b,
                 const float* __restrict__ W1, const float* __restrict__ b1,
                 const float* __restrict__ W2, const float* __restrict__ b2,
                 uint4* __restrict__ ws)
{
    const int lane = threadIdx.x;
    const int c15  = lane & 15;
    const int quad = lane >> 4;
    const int quad4 = quad << 2;
    const bool kv = (quad < 2);
    const int  kb = quad * 8;
    uint4* o = ws + lane * WS_SLOTS;
    FragU t; bf8 f;
    loadWfrag(Wq, 16, c15, kb, kv, 0.25f*1.44269504f, f); t.b = f; o[0] = t.u4;
    loadWfrag(Wk, 16, c15, kb, kv, 1.0f, f);              t.b = f; o[1] = t.u4;
    loadWfrag(Wv, 16, c15, kb, kv, 1.0f, f);              t.b = f; o[2] = t.u4;
    loadWfrag(W1, 32, c15,      kb, kv,   1.0f, f);       t.b = f; o[3] = t.u4;
    loadWfrag(W1, 32, c15 + 16, kb, kv,   1.0f, f);       t.b = f; o[4] = t.u4;
    loadWfrag(W2, 16, c15,      kb, true, 1.0f, f);       t.b = f; o[5] = t.u4;
    F4U z; z.f = make_float4(0.f, 0.f, 0.f, 0.f);
    F4U a, b;
    if (kv) {
        a.f = *(const float4*)(ln1g + kb); b.f = *(const float4*)(ln1g + kb + 4);
    } else { a = z; b = z; }
    o[6] = a.u4; o[7] = b.u4;
    if (kv) {
        a.f = *(const float4*)(ln1b + kb); b.f = *(const float4*)(ln1b + kb + 4);
    } else { a = z; b = z; }
    o[8] = a.u4; o[9] = b.u4;
    a.f = *(const float4*)(ln2g + quad4); o[10] = a.u4;
    a.f = *(const float4*)(ln2b + quad4); o[11] = a.u4;
    a.f = make_float4(b1[c15], b1[c15 + 16], b2[c15], 0.f);
    o[12] = a.u4;
}

__global__ __launch_bounds__(64, 4)
void tb_kernel(const float* __restrict__ x,
               const uint4* __restrict__ ws,
               float* __restrict__ out)
{
    __shared__ __align__(16) uint lds[ARENA];
    const int lane = threadIdx.x;
    const int c15  = lane & 15;
    const int quad = lane >> 4;
    const int quad4 = quad << 2;
    const size_t base = (size_t)blockIdx.x * (64 * 16);
    const f4 z4 = {0.f, 0.f, 0.f, 0.f};
    const bool kv = (quad < 2);          // K=16 mats: only quads 0,1 carry data
    const int  kb = quad * 8;
    const bool wrE = ((c15 & 1) == 0);

    // ---- prologue: 13 b128 loads from the pre-packed blob (L2-broadcast-hot)
    const uint4* wv = ws + lane * WS_SLOTS;
    FragU t;
    t.u4 = wv[0]; const bf8 fWq  = t.b;
    t.u4 = wv[1]; const bf8 fWk  = t.b;
    t.u4 = wv[2]; const bf8 fWv  = t.b;
    t.u4 = wv[3]; const bf8 fW1a = t.b;
    t.u4 = wv[4]; const bf8 fW1b = t.b;
    t.u4 = wv[5]; const bf8 fW2f = t.b;
    F4U fu;
    fu.u4 = wv[6];  const float4 g1a = fu.f;
    fu.u4 = wv[7];  const float4 g1b = fu.f;
    fu.u4 = wv[8];  const float4 b1a = fu.f;
    fu.u4 = wv[9];  const float4 b1b = fu.f;
    fu.u4 = wv[10]; const float4 g2  = fu.f;
    fu.u4 = wv[11]; const float4 b2v = fu.f;
    fu.u4 = wv[12];
    const float bu0 = fu.f.x, bu1 = fu.f.y, bo = fu.f.z;

    // ---- LN1 (fp32, TWO-PASS variance) -> bf16 A-fragments
    bf8 ah[4];
    {
        const float gg[8] = {g1a.x,g1a.y,g1a.z,g1a.w, g1b.x,g1b.y,g1b.z,g1b.w};
        const float bb[8] = {b1a.x,b1a.y,b1a.z,b1a.w, b1b.x,b1b.y,b1b.z,b1b.w};
        #pragma unroll
        for (int mt = 0; mt < 4; ++mt) {
            FragU Ah;
            if (kv) {
                const float4* xp = (const float4*)(x + base + (size_t)(mt*16 + c15)*16 + kb);
                float4 v0 = xp[0], v1 = xp[1];
                float xv[8] = {v0.x,v0.y,v0.z,v0.w, v1.x,v1.y,v1.z,v1.w};
                float s = 0.f;
                #pragma unroll
                for (int j = 0; j < 8; ++j) s += xv[j];
                s  += __shfl_xor(s, 16);    // combine half-rows (quads 0,1)
                float mu = s * 0.0625f;
                float s2 = 0.f;
                #pragma unroll
                for (int j = 0; j < 8; ++j) { float d = xv[j] - mu; s2 += d*d; }
                s2 += __shfl_xor(s2, 16);   // two-pass variance
                float var  = s2 * 0.0625f;
                float rstd = rsqrtf(var + 1e-5f);
                float h[8];
                #pragma unroll
                for (int j = 0; j < 8; ++j) h[j] = (xv[j]-mu)*rstd*gg[j] + bb[j];
                #pragma unroll
                for (int p = 0; p < 4; ++p) Ah.u[p] = packbf(h[2*p], h[2*p+1]);
            } else {
                Ah.u4 = make_uint4(0u,0u,0u,0u);
            }
            ah[mt] = Ah.b;
        }
    }

    // ---- projections -> packed bf16 LDS tiles
    //  sQ/sK: [tok][chpair] stride 12; sV: [ch][tokpair] stride 36
    #pragma unroll
    for (int mt = 0; mt < 4; ++mt) {
        f4 qc = MFMA(ah[mt], fWq, z4);
        f4 kc = MFMA(ah[mt], fWk, z4);
        f4 vc = MFMA(ah[mt], fWv, z4);
        #pragma unroll
        for (int r = 0; r < 4; ++r) {
            const int tok = mt*16 + quad4 + r;
            float qo = __shfl_xor(qc[r], 1);
            float ko = __shfl_xor(kc[r], 1);
            if (wrE) {
                lds[OQ + tok*12 + (c15>>1)] = packbf(qc[r], qo);
                lds[OK + tok*12 + (c15>>1)] = packbf(kc[r], ko);
            }
        }
        *(uint2*)(lds + OV + c15*36 + mt*8 + quad*2) =
            make_uint2(packbf(vc[0], vc[1]), packbf(vc[2], vc[3]));
    }
    __syncthreads();   // B1: packed Q/K/V visible

    // ---- S^T = K.Q^T, causal triangle only (10 MFMAs); scores in log2 units
    bf8 qb[4];                     // B-frags: B[k=ch][n=query] per query-tile
    #pragma unroll
    for (int qt = 0; qt < 4; ++qt) {
        FragU H;
        if (kv) H.u4 = *(const uint4*)(lds + OQ + (qt*16 + c15)*12 + quad4);
        else    H.u4 = make_uint4(0u,0u,0u,0u);
        qb[qt] = H.b;
    }
    f4 st[4][4];                   // st[kt][qt]: S^T[key=kt*16+quad4+r][query=qt*16+c15]
    #pragma unroll
    for (int kt = 0; kt < 4; ++kt) {
        FragU H;                   // A-frag: A[m=key][k=ch]
        if (kv) H.u4 = *(const uint4*)(lds + OK + (kt*16 + c15)*12 + quad4);
        else    H.u4 = make_uint4(0u,0u,0u,0u);
        bf8 ka = H.b;
        #pragma unroll
        for (int qt = 3; qt >= 0; --qt)
            if (qt >= kt)          // compile-time (unrolled): triangle only
                st[kt][qt] = MFMA(ka, qb[qt], z4);
    }
    // causal mask on diagonal tiles
    #pragma unroll
    for (int qt = 0; qt < 4; ++qt)
        #pragma unroll
        for (int r = 0; r < 4; ++r)
            st[qt][qt][r] = (quad4 + r <= c15) ? st[qt][qt][r] : -1e30f;

    // ---- direct softmax per query column (max3-friendly trees, native exp2)
    float linv[4];
    #pragma unroll
    for (int qt = 0; qt < 4; ++qt) {
        float mx = fmaxf(fmaxf(st[0][qt][0], st[0][qt][1]),
                         fmaxf(st[0][qt][2], st[0][qt][3]));
        #pragma unroll
        for (int kt = 1; kt < 4; ++kt) {
            if (kt <= qt) {
                float mk = fmaxf(fmaxf(st[kt][qt][0], st[kt][qt][1]),
                                 fmaxf(st[kt][qt][2], st[kt][qt][3]));
                mx = fmaxf(mx, mk);
            }
        }
        mx = fmaxf(mx, __shfl_xor(mx, 16));
        mx = fmaxf(mx, __shfl_xor(mx, 32));
        float l = 0.f;
        #pragma unroll
        for (int kt = 0; kt < 4; ++kt) {
            if (kt <= qt) {
                #pragma unroll
                for (int r = 0; r < 4; ++r) {
                    float p = __builtin_amdgcn_exp2f(st[kt][qt][r] - mx);
                    st[kt][qt][r] = p;
                    l += p;
                }
            }
        }
        l += __shfl_xor(l, 16);
        l += __shfl_xor(l, 32);
        linv[qt] = __builtin_amdgcn_rcpf(l);   // l in [1,64], well-conditioned
    }

    // ---- V A-fragments into registers BEFORE sP overwrites the arena
    bf8 va[2];                     // A[m=ch][k=key]
    #pragma unroll
    for (int kc = 0; kc < 2; ++kc) {
        FragU H;
        H.u4 = *(const uint4*)(lds + OV + c15*36 + kc*16 + quad4);
        va[kc] = H.b;
    }
    __syncthreads();   // B2a: all Q/K/V reads done; sP region writable

    // ---- pack P (bf16, unnormalized, in-lane key-pairs) -> sP [query][36]
    #pragma unroll
    for (int qt = 0; qt < 4; ++qt) {
        const int rowo = OP + (qt*16 + c15)*36 + quad*2;
        #pragma unroll
        for (int kt = 0; kt < 4; ++kt) {
            uint2 w;
            if (kt <= qt) {
                w.x = packbf(st[kt][qt][0], st[kt][qt][1]);
                w.y = packbf(st[kt][qt][2], st[kt][qt][3]);
            } else w = make_uint2(0u, 0u);
            *(uint2*)(lds + rowo + kt*8) = w;
        }
    }
    __syncthreads();   // B2b: sP visible

    // ---- y^T = V^T.P (6 MFMAs)
    f4 yt[4];                      // yt[qt]: y[query=qt*16+c15][ch=quad4+r]
    #pragma unroll
    for (int qt = 0; qt < 4; ++qt) {
        f4 acc = z4;
        #pragma unroll
        for (int kc = 0; kc < 2; ++kc) {
            if (kc == 0 || qt >= 2) {   // keys>=32 only for queries>=32
                FragU P_;
                P_.u4 = *(const uint4*)(lds + OP + (qt*16 + c15)*36 + kc*16 + quad4);
                acc = MFMA(va[kc], P_.b, acc);
            }
        }
        yt[qt] = acc;
    }

    // ---- residual 1 (y layout: query=qt*16+c15, ch=quad4+r)
    float x2v[4][4];
    #pragma unroll
    for (int qt = 0; qt < 4; ++qt) {
        float4 xv = *(const float4*)(x + base + (size_t)(qt*16 + c15)*16 + quad4);
        const float li = linv[qt];
        x2v[qt][0] = xv.x + yt[qt][0]*li;
        x2v[qt][1] = xv.y + yt[qt][1]*li;
        x2v[qt][2] = xv.z + yt[qt][2]*li;
        x2v[qt][3] = xv.w + yt[qt][3]*li;
    }
    __syncthreads();   // B3: sP reads done; sH2 region writable

    // ---- LN2 (two-pass, cross-quad butterfly) -> packed bf16 h2
    #pragma unroll
    for (int qt = 0; qt < 4; ++qt) {
        float s = x2v[qt][0]+x2v[qt][1]+x2v[qt][2]+x2v[qt][3];
        s += __shfl_xor(s, 16); s += __shfl_xor(s, 32);
        float mu = s * 0.0625f;
        float d0 = x2v[qt][0]-mu, d1 = x2v[qt][1]-mu,
              d2 = x2v[qt][2]-mu, d3 = x2v[qt][3]-mu;
        float s2 = d0*d0 + d1*d1 + d2*d2 + d3*d3;
        s2 += __shfl_xor(s2, 16); s2 += __shfl_xor(s2, 32);
        float rstd = rsqrtf(s2 * 0.0625f + 1e-5f);
        float h0 = d0*rstd*g2.x + b2v.x;
        float h1 = d1*rstd*g2.y + b2v.y;
        float h2_ = d2*rstd*g2.z + b2v.z;
        float h3 = d3*rstd*g2.w + b2v.w;
        *(uint2*)(lds + OH2 + (qt*16 + c15)*12 + quad*2) =
            make_uint2(packbf(h0, h1), packbf(h2_, h3));
    }
    __syncthreads();   // B4: sH2 visible

    // ---- h2 A-fragments
    bf8 a2[4];
    #pragma unroll
    for (int i = 0; i < 4; ++i) {
        FragU H;
        if (kv) H.u4 = *(const uint4*)(lds + OH2 + (i*16 + c15)*12 + quad4);
        else    H.u4 = make_uint4(0u,0u,0u,0u);
        a2[i] = H.b;
    }

    // ---- FFN1 (8 MFMAs) + gelu -> sU [64][20] @768 (disjoint from sH2)
    {
        f4 cb0 = {bu0, bu0, bu0, bu0};
        f4 cb1 = {bu1, bu1, bu1, bu1};
        #pragma unroll
        for (int mt = 0; mt < 4; ++mt) {
            f4 u0 = MFMA(a2[mt], fW1a, cb0);
            f4 u1 = MFMA(a2[mt], fW1b, cb1);
            #pragma unroll
            for (int r = 0; r < 4; ++r) {
                float g0 = gelu_fast(u0[r]);
                float g1 = gelu_fast(u1[r]);
                float go0 = __shfl_xor(g0, 1);
                float go1 = __shfl_xor(g1, 1);
                if (wrE) {
                    const int row = mt*16 + quad4 + r;
                    lds[OU + row*20 +     (c15 >> 1)] = packbf(g0, go0);
                    lds[OU + row*20 + 8 + (c15 >> 1)] = packbf(g1, go1);
                }
            }
        }
    }
    __syncthreads();   // B5: sU visible

    // ---- FFN2 (native K=32, 4 MFMAs)
    f4 fo[4];
    {
        f4 cb = {bo, bo, bo, bo};
        #pragma unroll
        for (int mt = 0; mt < 4; ++mt) {
            FragU H;                // A[m=tok][k=quad*8+j] spans all 32 ff dims
            H.u4 = *(const uint4*)(lds + OU + (mt*16 + c15)*20 + quad4);
            fo[mt] = MFMA(H.b, fW2f, cb);
        }
    }
    __syncthreads();   // B6: sU reads done; sF @0 writable
    #pragma unroll
    for (int mt = 0; mt < 4; ++mt)
        #pragma unroll
        for (int r = 0; r < 4; ++r)
            lds[OF + (mt*16 + quad4 + r)*20 + c15] = __float_as_uint(fo[mt][r]);
    __syncthreads();   // B7: sF visible

    // ---- final residual + coalesced store
    #pragma unroll
    for (int qt = 0; qt < 4; ++qt) {
        FragU F;
        F.u4 = *(const uint4*)(lds + OF + (qt*16 + c15)*20 + quad4);
        float4 o;
        o.x = x2v[qt][0] + __uint_as_float(F.u[0]);
        o.y = x2v[qt][1] + __uint_as_float(F.u[1]);
        o.z = x2v[qt][2] + __uint_as_float(F.u[2]);
        o.w = x2v[qt][3] + __uint_as_float(F.u[3]);
        *(float4*)(out + base + (size_t)(qt*16 + c15)*16 + quad4) = o;
    }
}

extern "C" void kernel_launch(void* const* d_in, const int* in_sizes, int n_in,
                              void* d_out, int out_size, void* d_ws, size_t ws_size,
                              hipStream_t stream) {
    const float* x     = (const float*)d_in[0];
    const float* Wk    = (const float*)d_in[1];
    const float* Wq    = (const float*)d_in[2];
    const float* Wv    = (const float*)d_in[3];
    const float* ln1_g = (const float*)d_in[4];
    const float* ln1_b = (const float*)d_in[5];
    const float* ln2_g = (const float*)d_in[6];
    const float* ln2_b = (const float*)d_in[7];
    const float* W1    = (const float*)d_in[8];
    const float* b1    = (const float*)d_in[9];
    const float* W2    = (const float*)d_in[10];
    const float* b2    = (const float*)d_in[11];
    float* out = (float*)d_out;
    uint4* ws = (uint4*)d_ws;

    prep_kernel<<<1, 64, 0, stream>>>(Wk, Wq, Wv, ln1_g, ln1_b, ln2_g, ln2_b,
                                      W1, b1, W2, b2, ws);
    const int n_blocks = in_sizes[0] / (64 * 16);   // 16384
    tb_kernel<<<n_blocks, 64, 0, stream>>>(x, ws, out);
}